// Round 1
// baseline (1803.203 us; speedup 1.0000x reference)
//
#include <hip/hip_runtime.h>
#include <hip/hip_bf16.h>
#include <cstdint>

// Problem constants
#define NE 16            // experts
#define D_ 2048          // d_model
#define F_ 1408          // ffn hidden
#define NTOK 8192        // B*S
#define NPAIR (NTOK * 2) // routed token-expert pairs
#define SHARED_BASE NPAIR
#define NTOT (NPAIR + NTOK) // + shared-expert rows

// Tiling
#define BM 64
#define BN 64
#define BK 64
#define LDK 72 // padded ushorts per LDS row (144B stride -> banks spread)

typedef __attribute__((ext_vector_type(8))) short short8;
typedef __attribute__((ext_vector_type(4))) float f32x4;

static __device__ __forceinline__ ushort f2bf(float f) {
    union { float f; unsigned u; } v; v.f = f;
    unsigned u = v.u;
    return (ushort)((u + 0x7FFFu + ((u >> 16) & 1u)) >> 16); // RNE
}

static __device__ __forceinline__ void cvt_store8(ushort* dst, const float* src) {
    const float4* s = reinterpret_cast<const float4*>(src);
    float4 a = s[0], b = s[1];
    short8 v;
    v[0] = (short)f2bf(a.x); v[1] = (short)f2bf(a.y);
    v[2] = (short)f2bf(a.z); v[3] = (short)f2bf(a.w);
    v[4] = (short)f2bf(b.x); v[5] = (short)f2bf(b.y);
    v[6] = (short)f2bf(b.z); v[7] = (short)f2bf(b.w);
    *reinterpret_cast<short8*>(dst) = v;
}

static __device__ __forceinline__ void store8_zero(ushort* dst) {
    short8 v = {};
    *reinterpret_cast<short8*>(dst) = v;
}

// ---------------- routing: one wave per token ----------------
__global__ __launch_bounds__(256) void k_route(const float* __restrict__ x,
                                               const float* __restrict__ gate_w,
                                               const float* __restrict__ expert_bias,
                                               int* __restrict__ topk_idx,
                                               float* __restrict__ topk_w) {
    const int wave = threadIdx.x >> 6;
    const int lane = threadIdx.x & 63;
    const int tok = blockIdx.x * 4 + wave;
    if (tok >= NTOK) return;
    const float* xr = x + (size_t)tok * D_;
    float xv[D_ / 64];
#pragma unroll
    for (int i = 0; i < D_ / 64; ++i) xv[i] = xr[lane + 64 * i];

    float logits[NE];
#pragma unroll
    for (int e = 0; e < NE; ++e) {
        const float* gw = gate_w + e * D_;
        float p = 0.f;
#pragma unroll
        for (int i = 0; i < D_ / 64; ++i) p += xv[i] * gw[lane + 64 * i];
#pragma unroll
        for (int off = 32; off > 0; off >>= 1) p += __shfl_xor(p, off, 64);
        logits[e] = p;
    }
    // top-2 by biased logits (lowest index wins ties, like jax top_k)
    int i1 = 0; float b1 = logits[0] + expert_bias[0];
#pragma unroll
    for (int e = 1; e < NE; ++e) {
        float b = logits[e] + expert_bias[e];
        if (b > b1) { b1 = b; i1 = e; }
    }
    int i2 = -1; float b2 = -3.4e38f;
#pragma unroll
    for (int e = 0; e < NE; ++e) {
        if (e == i1) continue;
        float b = logits[e] + expert_bias[e];
        if (b > b2) { b2 = b; i2 = e; }
    }
    // weights: softmax(unbiased logits) at {i1,i2}, renormalized
    // == softmax over the two selected logits
    float l1 = logits[i1], l2 = logits[i2];
    float m = fmaxf(l1, l2);
    float e1 = __expf(l1 - m), e2 = __expf(l2 - m);
    float s = e1 + e2;
    if (lane == 0) {
        topk_idx[tok * 2 + 0] = i1;
        topk_idx[tok * 2 + 1] = i2;
        topk_w[tok * 2 + 0] = e1 / s;
        topk_w[tok * 2 + 1] = e2 / s;
    }
}

// ---------------- tiny bookkeeping kernels ----------------
// meta layout (ints): [0:16) cnt, [16:32) cnt2, [32:49) off
__global__ void k_zero_meta(int* meta) {
    if (threadIdx.x < 64) meta[threadIdx.x] = 0;
}

__global__ __launch_bounds__(256) void k_count(const int* __restrict__ topk_idx,
                                               int* __restrict__ meta) {
    int t = blockIdx.x * 256 + threadIdx.x;
    if (t >= NTOK) return;
    atomicAdd(&meta[topk_idx[t * 2 + 0]], 1);
    atomicAdd(&meta[topk_idx[t * 2 + 1]], 1);
}

__global__ void k_prefix(int* meta) {
    if (threadIdx.x == 0) {
        int acc = 0;
        for (int e = 0; e < NE; ++e) { meta[32 + e] = acc; acc += meta[e]; }
        meta[32 + NE] = acc; // == NPAIR
    }
}

__global__ __launch_bounds__(256) void k_scatter(const int* __restrict__ topk_idx,
                                                 const float* __restrict__ topk_w,
                                                 int* __restrict__ meta,
                                                 int* __restrict__ tok_sorted,
                                                 float* __restrict__ w_sorted) {
    int t = blockIdx.x * 256 + threadIdx.x;
    if (t >= NTOK) return;
#pragma unroll
    for (int k = 0; k < 2; ++k) {
        int e = topk_idx[t * 2 + k];
        int p = atomicAdd(&meta[16 + e], 1);
        int idx = meta[32 + e] + p;
        tok_sorted[idx] = t;
        w_sorted[idx] = topk_w[t * 2 + k];
    }
}

// ---------------- pass A: h = silu(x@wg^T) * (x@wu^T), per expert ----------------
// grid: (F_/BN, NTOK/BM, NE+1); block 256 (4 waves, each 32x32 of the 64x64 tile)
__global__ __launch_bounds__(256) void k_ffn1(const float* __restrict__ x,
                                              const float* __restrict__ w_gate,
                                              const float* __restrict__ w_up,
                                              const float* __restrict__ sw_gate,
                                              const float* __restrict__ sw_up,
                                              const int* __restrict__ meta,
                                              const int* __restrict__ tok_sorted,
                                              ushort* __restrict__ Hbuf) {
    const int e = blockIdx.z;
    int n_e, base;
    if (e < NE) { n_e = meta[e]; base = meta[32 + e]; }
    else        { n_e = NTOK;    base = SHARED_BASE; }
    const int row0 = blockIdx.y * BM;
    if (row0 >= n_e) return;
    const int f0 = blockIdx.x * BN;
    const float* wg = (e < NE) ? w_gate + (size_t)e * F_ * D_ : sw_gate;
    const float* wu = (e < NE) ? w_up   + (size_t)e * F_ * D_ : sw_up;

    __shared__ __align__(16) ushort As[BM][LDK];
    __shared__ __align__(16) ushort Gs[BN][LDK];
    __shared__ __align__(16) ushort Us[BN][LDK];
    __shared__ int tks[BM];

    const int tid = threadIdx.x;
    if (tid < BM) {
        int r = row0 + tid;
        tks[tid] = (r < n_e) ? ((e < NE) ? tok_sorted[base + r] : r) : -1;
    }
    __syncthreads();

    f32x4 accg[2][2] = {{{0.f,0.f,0.f,0.f},{0.f,0.f,0.f,0.f}},{{0.f,0.f,0.f,0.f},{0.f,0.f,0.f,0.f}}};
    f32x4 accu[2][2] = {{{0.f,0.f,0.f,0.f},{0.f,0.f,0.f,0.f}},{{0.f,0.f,0.f,0.f},{0.f,0.f,0.f,0.f}}};
    const int wv = tid >> 6, lane = tid & 63;
    const int wr = (wv >> 1) * 32, wc = (wv & 1) * 32;
    const int fr = lane & 15, fq = lane >> 4;

    for (int k0 = 0; k0 < D_; k0 += BK) {
        // stage: 512 16B-chunks each for A, G, U; 2 chunks/thread each
#pragma unroll
        for (int cc = 0; cc < 2; ++cc) {
            int c = tid + cc * 256;
            int r = c >> 3, ch = c & 7;
            // A (tokens)
            int t = tks[r];
            if (t >= 0) cvt_store8(&As[r][ch * 8], x + (size_t)t * D_ + k0 + ch * 8);
            else        store8_zero(&As[r][ch * 8]);
            // G, U (weights; all rows valid)
            cvt_store8(&Gs[r][ch * 8], wg + (size_t)(f0 + r) * D_ + k0 + ch * 8);
            cvt_store8(&Us[r][ch * 8], wu + (size_t)(f0 + r) * D_ + k0 + ch * 8);
        }
        __syncthreads();
#pragma unroll
        for (int kk = 0; kk < 2; ++kk) {
            short8 af[2], gf[2], uf[2];
#pragma unroll
            for (int mm = 0; mm < 2; ++mm)
                af[mm] = *reinterpret_cast<const short8*>(&As[wr + mm * 16 + fr][kk * 32 + fq * 8]);
#pragma unroll
            for (int nn = 0; nn < 2; ++nn) {
                gf[nn] = *reinterpret_cast<const short8*>(&Gs[wc + nn * 16 + fr][kk * 32 + fq * 8]);
                uf[nn] = *reinterpret_cast<const short8*>(&Us[wc + nn * 16 + fr][kk * 32 + fq * 8]);
            }
#pragma unroll
            for (int mm = 0; mm < 2; ++mm)
#pragma unroll
                for (int nn = 0; nn < 2; ++nn) {
                    accg[mm][nn] = __builtin_amdgcn_mfma_f32_16x16x32_bf16(af[mm], gf[nn], accg[mm][nn], 0, 0, 0);
                    accu[mm][nn] = __builtin_amdgcn_mfma_f32_16x16x32_bf16(af[mm], uf[nn], accu[mm][nn], 0, 0, 0);
                }
        }
        __syncthreads();
    }

    // epilogue: h = silu(g)*u -> Hbuf[base+row][f] (bf16)
#pragma unroll
    for (int mm = 0; mm < 2; ++mm) {
#pragma unroll
        for (int r = 0; r < 4; ++r) {
            int lr = wr + mm * 16 + fq * 4 + r;
            int grow = row0 + lr;
            if (grow < n_e) {
#pragma unroll
                for (int nn = 0; nn < 2; ++nn) {
                    float g = accg[mm][nn][r];
                    float u = accu[mm][nn][r];
                    float h = (g / (1.f + __expf(-g))) * u;
                    int f = f0 + wc + nn * 16 + fr;
                    Hbuf[(size_t)(base + grow) * F_ + f] = f2bf(h);
                }
            }
        }
    }
}

// ---------------- pass B: out += w * (H @ wd^T) ----------------
// grid: (D_/BN, NTOK/BM, NE or 1); block 256
__global__ __launch_bounds__(256) void k_ffn2(const ushort* __restrict__ Hbuf,
                                              const float* __restrict__ w_down,
                                              const float* __restrict__ sw_down,
                                              const int* __restrict__ meta,
                                              const int* __restrict__ tok_sorted,
                                              const float* __restrict__ w_sorted,
                                              float* __restrict__ out,
                                              int shared_pass) {
    const int e = shared_pass ? NE : (int)blockIdx.z;
    int n_e, base;
    if (e < NE) { n_e = meta[e]; base = meta[32 + e]; }
    else        { n_e = NTOK;    base = SHARED_BASE; }
    const int row0 = blockIdx.y * BM;
    if (row0 >= n_e) return;
    const int d0 = blockIdx.x * BN;
    const float* wd = (e < NE) ? w_down + (size_t)e * D_ * F_ : sw_down;

    __shared__ __align__(16) ushort As[BM][LDK];
    __shared__ __align__(16) ushort Bs[BN][LDK];
    __shared__ int tks[BM];
    __shared__ float tws[BM];

    const int tid = threadIdx.x;
    if (tid < BM) {
        int r = row0 + tid;
        if (r < n_e) {
            tks[tid] = (e < NE) ? tok_sorted[base + r] : r;
            tws[tid] = (e < NE) ? w_sorted[base + r] : 1.0f;
        } else { tks[tid] = -1; tws[tid] = 0.f; }
    }
    __syncthreads();

    f32x4 acc[2][2] = {{{0.f,0.f,0.f,0.f},{0.f,0.f,0.f,0.f}},{{0.f,0.f,0.f,0.f},{0.f,0.f,0.f,0.f}}};
    const int wv = tid >> 6, lane = tid & 63;
    const int wr = (wv >> 1) * 32, wc = (wv & 1) * 32;
    const int fr = lane & 15, fq = lane >> 4;

    for (int k0 = 0; k0 < F_; k0 += BK) {
#pragma unroll
        for (int cc = 0; cc < 2; ++cc) {
            int c = tid + cc * 256;
            int r = c >> 3, ch = c & 7;
            int slot = row0 + r;
            if (slot < n_e) {
                *reinterpret_cast<short8*>(&As[r][ch * 8]) =
                    *reinterpret_cast<const short8*>(&Hbuf[(size_t)(base + slot) * F_ + k0 + ch * 8]);
            } else store8_zero(&As[r][ch * 8]);
            cvt_store8(&Bs[r][ch * 8], wd + (size_t)(d0 + r) * F_ + k0 + ch * 8);
        }
        __syncthreads();
#pragma unroll
        for (int kk = 0; kk < 2; ++kk) {
            short8 af[2], bf[2];
#pragma unroll
            for (int mm = 0; mm < 2; ++mm)
                af[mm] = *reinterpret_cast<const short8*>(&As[wr + mm * 16 + fr][kk * 32 + fq * 8]);
#pragma unroll
            for (int nn = 0; nn < 2; ++nn)
                bf[nn] = *reinterpret_cast<const short8*>(&Bs[wc + nn * 16 + fr][kk * 32 + fq * 8]);
#pragma unroll
            for (int mm = 0; mm < 2; ++mm)
#pragma unroll
                for (int nn = 0; nn < 2; ++nn)
                    acc[mm][nn] = __builtin_amdgcn_mfma_f32_16x16x32_bf16(af[mm], bf[nn], acc[mm][nn], 0, 0, 0);
        }
        __syncthreads();
    }

#pragma unroll
    for (int mm = 0; mm < 2; ++mm) {
#pragma unroll
        for (int r = 0; r < 4; ++r) {
            int lr = wr + mm * 16 + fq * 4 + r;
            int slot = row0 + lr;
            if (slot < n_e) {
                int t = tks[lr];
                float w = tws[lr];
#pragma unroll
                for (int nn = 0; nn < 2; ++nn) {
                    int d = d0 + wc + nn * 16 + fr;
                    float val = acc[mm][nn][r] * w;
                    if (shared_pass) out[(size_t)t * D_ + d] = val;
                    else atomicAdd(&out[(size_t)t * D_ + d], val);
                }
            }
        }
    }
}

extern "C" void kernel_launch(void* const* d_in, const int* in_sizes, int n_in,
                              void* d_out, int out_size, void* d_ws, size_t ws_size,
                              hipStream_t stream) {
    const float* x        = (const float*)d_in[0];
    const float* gate_w   = (const float*)d_in[1];
    const float* w_gate   = (const float*)d_in[2];
    const float* w_up     = (const float*)d_in[3];
    const float* w_down   = (const float*)d_in[4];
    const float* sw_gate  = (const float*)d_in[5];
    const float* sw_up    = (const float*)d_in[6];
    const float* sw_down  = (const float*)d_in[7];
    const float* expert_bias = (const float*)d_in[8];
    float* out = (float*)d_out;

    char* ws = (char*)d_ws;
    size_t off = 0;
    ushort* Hbuf = (ushort*)(ws + off); off += (size_t)NTOT * F_ * sizeof(ushort); // 69.2 MB
    int* tok_sorted = (int*)(ws + off); off += NPAIR * sizeof(int);
    float* w_sorted = (float*)(ws + off); off += NPAIR * sizeof(float);
    int* topk_idx = (int*)(ws + off); off += NTOK * 2 * sizeof(int);
    float* topk_w = (float*)(ws + off); off += NTOK * 2 * sizeof(float);
    int* meta = (int*)(ws + off); off += 256;

    k_route<<<NTOK / 4, 256, 0, stream>>>(x, gate_w, expert_bias, topk_idx, topk_w);
    k_zero_meta<<<1, 64, 0, stream>>>(meta);
    k_count<<<NTOK / 256, 256, 0, stream>>>(topk_idx, meta);
    k_prefix<<<1, 1, 0, stream>>>(meta);
    k_scatter<<<NTOK / 256, 256, 0, stream>>>(topk_idx, topk_w, meta, tok_sorted, w_sorted);

    dim3 g1(F_ / BN, NTOK / BM, NE + 1);
    k_ffn1<<<g1, 256, 0, stream>>>(x, w_gate, w_up, sw_gate, sw_up, meta, tok_sorted, Hbuf);

    dim3 g2s(D_ / BN, NTOK / BM, 1);
    k_ffn2<<<g2s, 256, 0, stream>>>(Hbuf, w_down, sw_down, meta, tok_sorted, w_sorted, out, 1);
    dim3 g2r(D_ / BN, NTOK / BM, NE);
    k_ffn2<<<g2r, 256, 0, stream>>>(Hbuf, w_down, sw_down, meta, tok_sorted, w_sorted, out, 0);
}

// Round 2
// 1351.665 us; speedup vs baseline: 1.3341x; 1.3341x over previous
//
#include <hip/hip_runtime.h>
#include <hip/hip_bf16.h>
#include <cstdint>

// Problem constants
#define NE 16            // experts
#define D_ 2048          // d_model
#define F_ 1408          // ffn hidden
#define NTOK 8192        // B*S
#define NPAIR (NTOK * 2) // routed token-expert pairs
#define SHARED_BASE NPAIR
#define NTOT (NPAIR + NTOK) // + shared-expert rows

// Tiling (m97-style 128x128, BK=64, 8 waves)
#define BM 128
#define BN 128
#define BK 64

typedef __attribute__((ext_vector_type(8))) short short8;
typedef __attribute__((ext_vector_type(4))) float f32x4;

static __device__ __forceinline__ ushort f2bf(float f) {
    union { float f; unsigned u; } v; v.f = f;
    unsigned u = v.u;
    return (ushort)((u + 0x7FFFu + ((u >> 16) & 1u)) >> 16); // RNE
}

static __device__ __forceinline__ void cvt_store8(ushort* dst, const float* src) {
    const float4* s = reinterpret_cast<const float4*>(src);
    float4 a = s[0], b = s[1];
    short8 v;
    v[0] = (short)f2bf(a.x); v[1] = (short)f2bf(a.y);
    v[2] = (short)f2bf(a.z); v[3] = (short)f2bf(a.w);
    v[4] = (short)f2bf(b.x); v[5] = (short)f2bf(b.y);
    v[6] = (short)f2bf(b.z); v[7] = (short)f2bf(b.w);
    *reinterpret_cast<short8*>(dst) = v;
}

// async global->LDS, 16B per lane; LDS dest must be wave-uniform base (+lane*16 implicit)
static __device__ __forceinline__ void gll16(const void* g, void* l) {
    __builtin_amdgcn_global_load_lds((const __attribute__((address_space(1))) void*)g,
                                     (__attribute__((address_space(3))) void*)l, 16, 0, 0);
}

// ---------------- f32 -> bf16 conversion (grid-stride, 8 elems/thread) ----------------
__global__ __launch_bounds__(256) void k_cvt(const float* __restrict__ src,
                                             ushort* __restrict__ dst, int n8) {
    int i = blockIdx.x * 256 + threadIdx.x;
    int stride = gridDim.x * 256;
    for (; i < n8; i += stride) cvt_store8(dst + (size_t)i * 8, src + (size_t)i * 8);
}

// ---------------- routing: one wave per token ----------------
__global__ __launch_bounds__(256) void k_route(const float* __restrict__ x,
                                               const float* __restrict__ gate_w,
                                               const float* __restrict__ expert_bias,
                                               int* __restrict__ topk_idx,
                                               float* __restrict__ topk_w) {
    const int wave = threadIdx.x >> 6;
    const int lane = threadIdx.x & 63;
    const int tok = blockIdx.x * 4 + wave;
    if (tok >= NTOK) return;
    const float* xr = x + (size_t)tok * D_;
    float xv[D_ / 64];
#pragma unroll
    for (int i = 0; i < D_ / 64; ++i) xv[i] = xr[lane + 64 * i];

    float logits[NE];
#pragma unroll
    for (int e = 0; e < NE; ++e) {
        const float* gw = gate_w + e * D_;
        float p = 0.f;
#pragma unroll
        for (int i = 0; i < D_ / 64; ++i) p += xv[i] * gw[lane + 64 * i];
#pragma unroll
        for (int off = 32; off > 0; off >>= 1) p += __shfl_xor(p, off, 64);
        logits[e] = p;
    }
    int i1 = 0; float b1 = logits[0] + expert_bias[0];
#pragma unroll
    for (int e = 1; e < NE; ++e) {
        float b = logits[e] + expert_bias[e];
        if (b > b1) { b1 = b; i1 = e; }
    }
    int i2 = -1; float b2 = -3.4e38f;
#pragma unroll
    for (int e = 0; e < NE; ++e) {
        if (e == i1) continue;
        float b = logits[e] + expert_bias[e];
        if (b > b2) { b2 = b; i2 = e; }
    }
    float l1 = logits[i1], l2 = logits[i2];
    float m = fmaxf(l1, l2);
    float e1 = __expf(l1 - m), e2 = __expf(l2 - m);
    float s = e1 + e2;
    if (lane == 0) {
        topk_idx[tok * 2 + 0] = i1;
        topk_idx[tok * 2 + 1] = i2;
        topk_w[tok * 2 + 0] = e1 / s;
        topk_w[tok * 2 + 1] = e2 / s;
    }
}

// ---------------- bookkeeping ----------------
// meta (ints): [0:16) cnt, [16:32) cnt2, [32:49) off
__global__ void k_zero_meta(int* meta) {
    if (threadIdx.x < 64) meta[threadIdx.x] = 0;
}

__global__ __launch_bounds__(256) void k_count(const int* __restrict__ topk_idx,
                                               int* __restrict__ meta) {
    int t = blockIdx.x * 256 + threadIdx.x;
    if (t >= NTOK) return;
    atomicAdd(&meta[topk_idx[t * 2 + 0]], 1);
    atomicAdd(&meta[topk_idx[t * 2 + 1]], 1);
}

__global__ void k_prefix(int* meta) {
    if (threadIdx.x == 0) {
        int acc = 0;
        for (int e = 0; e < NE; ++e) { meta[32 + e] = acc; acc += meta[e]; }
        meta[32 + NE] = acc;
    }
}

__global__ __launch_bounds__(256) void k_scatter(const int* __restrict__ topk_idx,
                                                 const float* __restrict__ topk_w,
                                                 int* __restrict__ meta,
                                                 int* __restrict__ tok_sorted,
                                                 float* __restrict__ w_sorted) {
    int t = blockIdx.x * 256 + threadIdx.x;
    if (t >= NTOK) return;
#pragma unroll
    for (int k = 0; k < 2; ++k) {
        int e = topk_idx[t * 2 + k];
        int p = atomicAdd(&meta[16 + e], 1);
        int idx = meta[32 + e] + p;
        tok_sorted[idx] = t;
        w_sorted[idx] = topk_w[t * 2 + k];
    }
}

// ---------------- pass A: h = silu(x@wg^T) * (x@wu^T) ----------------
// grid: (F_/BN=11, NTOK/BM=64, NE+1); block 512 (8 waves as 4M x 2N, each 32x64)
__global__ __launch_bounds__(512) void k_ffn1(const ushort* __restrict__ xb,
                                              const ushort* __restrict__ wgb,
                                              const ushort* __restrict__ wub,
                                              const ushort* __restrict__ swgb,
                                              const ushort* __restrict__ swub,
                                              const int* __restrict__ meta,
                                              const int* __restrict__ tok_sorted,
                                              ushort* __restrict__ Hbuf) {
    const int e = blockIdx.z;
    int n_e, base;
    if (e < NE) { n_e = meta[e]; base = meta[32 + e]; }
    else        { n_e = NTOK;    base = SHARED_BASE; }
    const int row0 = blockIdx.y * BM;
    if (row0 >= n_e) return;
    const int f0 = blockIdx.x * BN;
    const ushort* wg = (e < NE) ? wgb + (size_t)e * F_ * D_ : swgb;
    const ushort* wu = (e < NE) ? wub + (size_t)e * F_ * D_ : swub;

    __shared__ __align__(16) ushort As[BM * BK]; // 16 KB, linear [row][k]
    __shared__ __align__(16) ushort Gs[BN * BK];
    __shared__ __align__(16) ushort Us[BN * BK];
    __shared__ int tks[BM];

    const int tid = threadIdx.x;
    const int wv = tid >> 6, lane = tid & 63;
    if (tid < BM) {
        int r = row0 + tid;
        tks[tid] = (r < n_e) ? ((e < NE) ? tok_sorted[base + r] : r) : 0; // clamp to valid addr
    }
    __syncthreads();

    // chunk mapping: tile = 1024 x 16B chunks; wave w round j covers [j*512 + w*64, +64)
    const int c0 = wv * 64 + lane, c1 = c0 + 512;
    const int rA0 = c0 >> 3, ch0 = (c0 & 7) * 8;
    const int rA1 = c1 >> 3, ch1 = (c1 & 7) * 8;
    const ushort* srcA0 = xb + (size_t)tks[rA0] * D_ + ch0;
    const ushort* srcA1 = xb + (size_t)tks[rA1] * D_ + ch1;
    const ushort* srcG0 = wg + (size_t)(f0 + rA0) * D_ + ch0;
    const ushort* srcG1 = wg + (size_t)(f0 + rA1) * D_ + ch1;
    const ushort* srcU0 = wu + (size_t)(f0 + rA0) * D_ + ch0;
    const ushort* srcU1 = wu + (size_t)(f0 + rA1) * D_ + ch1;
    char* lA = (char*)As + wv * 1024;
    char* lG = (char*)Gs + wv * 1024;
    char* lU = (char*)Us + wv * 1024;

    f32x4 accg[2][4] = {}; f32x4 accu[2][4] = {};
    const int wm = (wv >> 1) * 32, wn = (wv & 1) * 64;
    const int fr = lane & 15, fq = lane >> 4;

    for (int k0 = 0; k0 < D_; k0 += BK) {
        gll16(srcA0 + k0, lA); gll16(srcA1 + k0, lA + 8192);
        gll16(srcG0 + k0, lG); gll16(srcG1 + k0, lG + 8192);
        gll16(srcU0 + k0, lU); gll16(srcU1 + k0, lU + 8192);
        __syncthreads(); // waits vmcnt(0)
#pragma unroll
        for (int kk = 0; kk < 2; ++kk) {
            short8 af[2], gf[4], uf[4];
#pragma unroll
            for (int mm = 0; mm < 2; ++mm)
                af[mm] = *reinterpret_cast<const short8*>(&As[(wm + mm * 16 + fr) * BK + kk * 32 + fq * 8]);
#pragma unroll
            for (int nn = 0; nn < 4; ++nn) {
                gf[nn] = *reinterpret_cast<const short8*>(&Gs[(wn + nn * 16 + fr) * BK + kk * 32 + fq * 8]);
                uf[nn] = *reinterpret_cast<const short8*>(&Us[(wn + nn * 16 + fr) * BK + kk * 32 + fq * 8]);
            }
#pragma unroll
            for (int mm = 0; mm < 2; ++mm)
#pragma unroll
                for (int nn = 0; nn < 4; ++nn) {
                    accg[mm][nn] = __builtin_amdgcn_mfma_f32_16x16x32_bf16(af[mm], gf[nn], accg[mm][nn], 0, 0, 0);
                    accu[mm][nn] = __builtin_amdgcn_mfma_f32_16x16x32_bf16(af[mm], uf[nn], accu[mm][nn], 0, 0, 0);
                }
        }
        __syncthreads();
    }

    // epilogue: h = silu(g)*u -> Hbuf bf16
#pragma unroll
    for (int mm = 0; mm < 2; ++mm) {
#pragma unroll
        for (int r = 0; r < 4; ++r) {
            int lr = wm + mm * 16 + fq * 4 + r;
            int grow = row0 + lr;
            if (grow < n_e) {
                ushort* hrow = Hbuf + (size_t)(base + grow) * F_ + f0 + wn;
#pragma unroll
                for (int nn = 0; nn < 4; ++nn) {
                    float g = accg[mm][nn][r];
                    float u = accu[mm][nn][r];
                    float h = (g / (1.f + __expf(-g))) * u;
                    hrow[nn * 16 + fr] = f2bf(h);
                }
            }
        }
    }
}

// ---------------- pass B: out (+)= w * (H @ wd^T) ----------------
// grid: (D_/BN=16, NTOK/BM=64, NE or 1); block 512
__global__ __launch_bounds__(512) void k_ffn2(const ushort* __restrict__ Hbuf,
                                              const ushort* __restrict__ wdb,
                                              const ushort* __restrict__ swdb,
                                              const int* __restrict__ meta,
                                              const int* __restrict__ tok_sorted,
                                              const float* __restrict__ w_sorted,
                                              float* __restrict__ out,
                                              int shared_pass) {
    const int e = shared_pass ? NE : (int)blockIdx.z;
    int n_e, base;
    if (e < NE) { n_e = meta[e]; base = meta[32 + e]; }
    else        { n_e = NTOK;    base = SHARED_BASE; }
    const int row0 = blockIdx.y * BM;
    if (row0 >= n_e) return;
    const int d0 = blockIdx.x * BN;
    const ushort* wd = (e < NE) ? wdb + (size_t)e * D_ * F_ : swdb;

    __shared__ __align__(16) ushort As[BM * BK];
    __shared__ __align__(16) ushort Bs[BN * BK];
    __shared__ int tks[BM];
    __shared__ float tws[BM];

    const int tid = threadIdx.x;
    const int wv = tid >> 6, lane = tid & 63;
    if (tid < BM) {
        int r = row0 + tid;
        if (r < n_e) {
            tks[tid] = (e < NE) ? tok_sorted[base + r] : r;
            tws[tid] = (e < NE) ? w_sorted[base + r] : 1.0f;
        } else { tks[tid] = -1; tws[tid] = 0.f; }
    }
    __syncthreads();

    const int c0 = wv * 64 + lane, c1 = c0 + 512;
    const int rA0 = c0 >> 3, ch0 = (c0 & 7) * 8;
    const int rA1 = c1 >> 3, ch1 = (c1 & 7) * 8;
    // H rows for this expert are contiguous slots [base+row0, ...); tail reads stay in-bounds of ws
    const ushort* srcA0 = Hbuf + (size_t)(base + row0 + rA0) * F_ + ch0;
    const ushort* srcA1 = Hbuf + (size_t)(base + row0 + rA1) * F_ + ch1;
    const ushort* srcB0 = wd + (size_t)(d0 + rA0) * F_ + ch0;
    const ushort* srcB1 = wd + (size_t)(d0 + rA1) * F_ + ch1;
    char* lA = (char*)As + wv * 1024;
    char* lB = (char*)Bs + wv * 1024;

    f32x4 acc[2][4] = {};
    const int wm = (wv >> 1) * 32, wn = (wv & 1) * 64;
    const int fr = lane & 15, fq = lane >> 4;

    for (int k0 = 0; k0 < F_; k0 += BK) {
        gll16(srcA0 + k0, lA); gll16(srcA1 + k0, lA + 8192);
        gll16(srcB0 + k0, lB); gll16(srcB1 + k0, lB + 8192);
        __syncthreads();
#pragma unroll
        for (int kk = 0; kk < 2; ++kk) {
            short8 af[2], bf[4];
#pragma unroll
            for (int mm = 0; mm < 2; ++mm)
                af[mm] = *reinterpret_cast<const short8*>(&As[(wm + mm * 16 + fr) * BK + kk * 32 + fq * 8]);
#pragma unroll
            for (int nn = 0; nn < 4; ++nn)
                bf[nn] = *reinterpret_cast<const short8*>(&Bs[(wn + nn * 16 + fr) * BK + kk * 32 + fq * 8]);
#pragma unroll
            for (int mm = 0; mm < 2; ++mm)
#pragma unroll
                for (int nn = 0; nn < 4; ++nn)
                    acc[mm][nn] = __builtin_amdgcn_mfma_f32_16x16x32_bf16(af[mm], bf[nn], acc[mm][nn], 0, 0, 0);
        }
        __syncthreads();
    }

#pragma unroll
    for (int mm = 0; mm < 2; ++mm) {
#pragma unroll
        for (int r = 0; r < 4; ++r) {
            int lr = wm + mm * 16 + fq * 4 + r;
            int slot = row0 + lr;
            if (slot < n_e) {
                int t = tks[lr];
                float w = tws[lr];
                float* orow = out + (size_t)t * D_ + d0 + wn;
#pragma unroll
                for (int nn = 0; nn < 4; ++nn) {
                    float val = acc[mm][nn][r] * w;
                    if (shared_pass) orow[nn * 16 + fr] = val;
                    else atomicAdd(&orow[nn * 16 + fr], val);
                }
            }
        }
    }
}

extern "C" void kernel_launch(void* const* d_in, const int* in_sizes, int n_in,
                              void* d_out, int out_size, void* d_ws, size_t ws_size,
                              hipStream_t stream) {
    const float* x        = (const float*)d_in[0];
    const float* gate_w   = (const float*)d_in[1];
    const float* w_gate   = (const float*)d_in[2];
    const float* w_up     = (const float*)d_in[3];
    const float* w_down   = (const float*)d_in[4];
    const float* sw_gate  = (const float*)d_in[5];
    const float* sw_up    = (const float*)d_in[6];
    const float* sw_down  = (const float*)d_in[7];
    const float* expert_bias = (const float*)d_in[8];
    float* out = (float*)d_out;

    const size_t NW = (size_t)NE * F_ * D_;   // 46.1M elems per routed weight tensor
    const size_t NSW = (size_t)F_ * D_;       // 2.88M per shared tensor
    const size_t NX = (size_t)NTOK * D_;

    char* ws = (char*)d_ws;
    size_t off = 0;
    ushort* xb   = (ushort*)(ws + off); off += NX * 2;
    ushort* wgb  = (ushort*)(ws + off); off += NW * 2;
    ushort* wub  = (ushort*)(ws + off); off += NW * 2;
    ushort* wdb  = (ushort*)(ws + off); off += NW * 2;
    ushort* swgb = (ushort*)(ws + off); off += NSW * 2;
    ushort* swub = (ushort*)(ws + off); off += NSW * 2;
    ushort* swdb = (ushort*)(ws + off); off += NSW * 2;
    ushort* Hbuf = (ushort*)(ws + off); off += (size_t)NTOT * F_ * 2;
    int* tok_sorted = (int*)(ws + off); off += NPAIR * sizeof(int);
    float* w_sorted = (float*)(ws + off); off += NPAIR * sizeof(float);
    int* topk_idx = (int*)(ws + off); off += NTOK * 2 * sizeof(int);
    float* topk_w = (float*)(ws + off); off += NTOK * 2 * sizeof(float);
    int* meta = (int*)(ws + off); off += 256;

    // routing (f32 for exact expert selection)
    k_route<<<NTOK / 4, 256, 0, stream>>>(x, gate_w, expert_bias, topk_idx, topk_w);
    k_zero_meta<<<1, 64, 0, stream>>>(meta);
    k_count<<<NTOK / 256, 256, 0, stream>>>(topk_idx, meta);
    k_prefix<<<1, 1, 0, stream>>>(meta);
    k_scatter<<<NTOK / 256, 256, 0, stream>>>(topk_idx, topk_w, meta, tok_sorted, w_sorted);

    // one-time bf16 conversion
    auto cvt = [&](const float* s, ushort* d, size_t n) {
        int n8 = (int)(n / 8);
        int blocks = (n8 + 255) / 256;
        if (blocks > 4096) blocks = 4096;
        k_cvt<<<blocks, 256, 0, stream>>>(s, d, n8);
    };
    cvt(x, xb, NX);
    cvt(w_gate, wgb, NW);
    cvt(w_up, wub, NW);
    cvt(w_down, wdb, NW);
    cvt(sw_gate, swgb, NSW);
    cvt(sw_up, swub, NSW);
    cvt(sw_down, swdb, NSW);

    dim3 g1(F_ / BN, NTOK / BM, NE + 1);
    k_ffn1<<<g1, 512, 0, stream>>>(xb, wgb, wub, swgb, swub, meta, tok_sorted, Hbuf);

    dim3 g2s(D_ / BN, NTOK / BM, 1);
    k_ffn2<<<g2s, 512, 0, stream>>>(Hbuf, wdb, swdb, meta, tok_sorted, w_sorted, out, 1);
    dim3 g2r(D_ / BN, NTOK / BM, NE);
    k_ffn2<<<g2r, 512, 0, stream>>>(Hbuf, wdb, swdb, meta, tok_sorted, w_sorted, out, 0);
}

// Round 3
// 1102.818 us; speedup vs baseline: 1.6351x; 1.2256x over previous
//
#include <hip/hip_runtime.h>
#include <hip/hip_bf16.h>
#include <cstdint>

// Problem constants
#define NE 16            // experts
#define D_ 2048          // d_model
#define F_ 1408          // ffn hidden
#define NTOK 8192        // B*S
#define NPAIR (NTOK * 2) // routed token-expert pairs
#define SHARED_BASE NPAIR
#define NTOT (NPAIR + NTOK) // + shared-expert rows

// Tiling (128x128, BK=64, 8 waves)
#define BM 128
#define BN 128
#define BK 64

typedef __attribute__((ext_vector_type(8))) short short8;
typedef __attribute__((ext_vector_type(4))) float f32x4;

static __device__ __forceinline__ ushort f2bf(float f) {
    union { float f; unsigned u; } v; v.f = f;
    unsigned u = v.u;
    return (ushort)((u + 0x7FFFu + ((u >> 16) & 1u)) >> 16); // RNE
}

static __device__ __forceinline__ void cvt_store8(ushort* dst, const float* src) {
    const float4* s = reinterpret_cast<const float4*>(src);
    float4 a = s[0], b = s[1];
    short8 v;
    v[0] = (short)f2bf(a.x); v[1] = (short)f2bf(a.y);
    v[2] = (short)f2bf(a.z); v[3] = (short)f2bf(a.w);
    v[4] = (short)f2bf(b.x); v[5] = (short)f2bf(b.y);
    v[6] = (short)f2bf(b.z); v[7] = (short)f2bf(b.w);
    *reinterpret_cast<short8*>(dst) = v;
}

// async global->LDS, 16B per lane; LDS dest = wave-uniform base + lane*16 (linear)
static __device__ __forceinline__ void gll16(const void* g, void* l) {
    __builtin_amdgcn_global_load_lds((const __attribute__((address_space(1))) void*)g,
                                     (__attribute__((address_space(3))) void*)l, 16, 0, 0);
}

// ---------------- f32 -> bf16 conversion ----------------
__global__ __launch_bounds__(256) void k_cvt(const float* __restrict__ src,
                                             ushort* __restrict__ dst, int n8) {
    int i = blockIdx.x * 256 + threadIdx.x;
    int stride = gridDim.x * 256;
    for (; i < n8; i += stride) cvt_store8(dst + (size_t)i * 8, src + (size_t)i * 8);
}

// ---------------- routing: one wave per token ----------------
__global__ __launch_bounds__(256) void k_route(const float* __restrict__ x,
                                               const float* __restrict__ gate_w,
                                               const float* __restrict__ expert_bias,
                                               int* __restrict__ topk_idx,
                                               float* __restrict__ topk_w) {
    const int wave = threadIdx.x >> 6;
    const int lane = threadIdx.x & 63;
    const int tok = blockIdx.x * 4 + wave;
    if (tok >= NTOK) return;
    const float* xr = x + (size_t)tok * D_;
    float xv[D_ / 64];
#pragma unroll
    for (int i = 0; i < D_ / 64; ++i) xv[i] = xr[lane + 64 * i];

    float logits[NE];
#pragma unroll
    for (int e = 0; e < NE; ++e) {
        const float* gw = gate_w + e * D_;
        float p = 0.f;
#pragma unroll
        for (int i = 0; i < D_ / 64; ++i) p += xv[i] * gw[lane + 64 * i];
#pragma unroll
        for (int off = 32; off > 0; off >>= 1) p += __shfl_xor(p, off, 64);
        logits[e] = p;
    }
    int i1 = 0; float b1 = logits[0] + expert_bias[0];
#pragma unroll
    for (int e = 1; e < NE; ++e) {
        float b = logits[e] + expert_bias[e];
        if (b > b1) { b1 = b; i1 = e; }
    }
    int i2 = -1; float b2 = -3.4e38f;
#pragma unroll
    for (int e = 0; e < NE; ++e) {
        if (e == i1) continue;
        float b = logits[e] + expert_bias[e];
        if (b > b2) { b2 = b; i2 = e; }
    }
    float l1 = logits[i1], l2 = logits[i2];
    float m = fmaxf(l1, l2);
    float e1 = __expf(l1 - m), e2 = __expf(l2 - m);
    float s = e1 + e2;
    if (lane == 0) {
        topk_idx[tok * 2 + 0] = i1;
        topk_idx[tok * 2 + 1] = i2;
        topk_w[tok * 2 + 0] = e1 / s;
        topk_w[tok * 2 + 1] = e2 / s;
    }
}

// ---------------- bookkeeping ----------------
// meta (ints): [0:16) cnt, [16:32) cnt2, [32:49) off
__global__ void k_zero_meta(int* meta) {
    if (threadIdx.x < 64) meta[threadIdx.x] = 0;
}

__global__ __launch_bounds__(256) void k_count(const int* __restrict__ topk_idx,
                                               int* __restrict__ meta) {
    int t = blockIdx.x * 256 + threadIdx.x;
    if (t >= NTOK) return;
    atomicAdd(&meta[topk_idx[t * 2 + 0]], 1);
    atomicAdd(&meta[topk_idx[t * 2 + 1]], 1);
}

__global__ void k_prefix(int* meta) {
    if (threadIdx.x == 0) {
        int acc = 0;
        for (int e = 0; e < NE; ++e) { meta[32 + e] = acc; acc += meta[e]; }
        meta[32 + NE] = acc;
    }
}

__global__ __launch_bounds__(256) void k_scatter(const int* __restrict__ topk_idx,
                                                 const float* __restrict__ topk_w,
                                                 int* __restrict__ meta,
                                                 int* __restrict__ tok_sorted,
                                                 float* __restrict__ w_sorted) {
    int t = blockIdx.x * 256 + threadIdx.x;
    if (t >= NTOK) return;
#pragma unroll
    for (int k = 0; k < 2; ++k) {
        int e = topk_idx[t * 2 + k];
        int p = atomicAdd(&meta[16 + e], 1);
        int idx = meta[32 + e] + p;
        tok_sorted[idx] = t;
        w_sorted[idx] = topk_w[t * 2 + k];
    }
}

// ---------------- pass A: h = w_route * silu(x@wg^T) * (x@wu^T) ----------------
// grid: (F_/BN=11, rows/BM, NE+1); block 512 (8 waves as 4M x 2N, each 32x64)
// LDS layout: linear [row][64] ushorts, but LDS chunk j of row r holds GLOBAL chunk j^(r&7)
// (swizzle applied on the global source for global_load_lds, and on the ds_read side).
__global__ __launch_bounds__(512) void k_ffn1(const ushort* __restrict__ xb,
                                              const ushort* __restrict__ wgb,
                                              const ushort* __restrict__ wub,
                                              const ushort* __restrict__ swgb,
                                              const ushort* __restrict__ swub,
                                              const int* __restrict__ meta,
                                              const int* __restrict__ tok_sorted,
                                              const float* __restrict__ w_sorted,
                                              ushort* __restrict__ Hbuf) {
    const int e = blockIdx.z;
    int n_e, base;
    if (e < NE) { n_e = meta[e]; base = meta[32 + e]; }
    else        { n_e = NTOK;    base = SHARED_BASE; }
    const int row0 = blockIdx.y * BM;
    if (row0 >= n_e) return;
    const int f0 = blockIdx.x * BN;
    const ushort* wg = (e < NE) ? wgb + (size_t)e * F_ * D_ : swgb;
    const ushort* wu = (e < NE) ? wub + (size_t)e * F_ * D_ : swub;

    __shared__ __align__(16) ushort As[BM * BK]; // 16 KB each
    __shared__ __align__(16) ushort Gs[BN * BK];
    __shared__ __align__(16) ushort Us[BN * BK];
    __shared__ int tks[BM];
    __shared__ float tws[BM];

    const int tid = threadIdx.x;
    const int wv = tid >> 6, lane = tid & 63;
    if (tid < BM) {
        int r = row0 + tid;
        if (r < n_e) {
            tks[tid] = (e < NE) ? tok_sorted[base + r] : r;
            tws[tid] = (e < NE) ? w_sorted[base + r] : 1.0f;
        } else { tks[tid] = 0; tws[tid] = 0.f; }
    }
    __syncthreads();

    // staging chunk mapping: 1024 chunks of 16B; this lane's 2 chunks
    const int c0 = wv * 64 + lane, c1 = c0 + 512;
    const int rA0 = c0 >> 3, rA1 = c1 >> 3;
    const int ch0 = ((c0 & 7) ^ (rA0 & 7)) * 8; // swizzled source column (ushorts)
    const int ch1 = ((c1 & 7) ^ (rA1 & 7)) * 8;
    const ushort* srcA0 = xb + (size_t)tks[rA0] * D_ + ch0;
    const ushort* srcA1 = xb + (size_t)tks[rA1] * D_ + ch1;
    const ushort* srcG0 = wg + (size_t)(f0 + rA0) * D_ + ch0;
    const ushort* srcG1 = wg + (size_t)(f0 + rA1) * D_ + ch1;
    const ushort* srcU0 = wu + (size_t)(f0 + rA0) * D_ + ch0;
    const ushort* srcU1 = wu + (size_t)(f0 + rA1) * D_ + ch1;
    char* lA = (char*)As + wv * 1024;
    char* lG = (char*)Gs + wv * 1024;
    char* lU = (char*)Us + wv * 1024;

    f32x4 accg[2][4] = {}; f32x4 accu[2][4] = {};
    const int wm = (wv >> 1) * 32, wn = (wv & 1) * 64;
    const int fr = lane & 15, fq = lane >> 4;
    const int sw = fr & 7;
    // swizzled ds_read column (ushorts) for kk=0/1
    const int rc0 = ((fq ^ sw) * 8);
    const int rc1 = (((4 + fq) ^ sw) * 8);

    for (int k0 = 0; k0 < D_; k0 += BK) {
        gll16(srcA0 + k0, lA); gll16(srcA1 + k0, lA + 8192);
        gll16(srcG0 + k0, lG); gll16(srcG1 + k0, lG + 8192);
        gll16(srcU0 + k0, lU); gll16(srcU1 + k0, lU + 8192);
        __syncthreads();
#pragma unroll
        for (int kk = 0; kk < 2; ++kk) {
            const int rc = kk ? rc1 : rc0;
            short8 af[2], gf[4], uf[4];
#pragma unroll
            for (int mm = 0; mm < 2; ++mm)
                af[mm] = *reinterpret_cast<const short8*>(&As[(wm + mm * 16 + fr) * BK + rc]);
#pragma unroll
            for (int nn = 0; nn < 4; ++nn) {
                gf[nn] = *reinterpret_cast<const short8*>(&Gs[(wn + nn * 16 + fr) * BK + rc]);
                uf[nn] = *reinterpret_cast<const short8*>(&Us[(wn + nn * 16 + fr) * BK + rc]);
            }
#pragma unroll
            for (int mm = 0; mm < 2; ++mm)
#pragma unroll
                for (int nn = 0; nn < 4; ++nn) {
                    accg[mm][nn] = __builtin_amdgcn_mfma_f32_16x16x32_bf16(af[mm], gf[nn], accg[mm][nn], 0, 0, 0);
                    accu[mm][nn] = __builtin_amdgcn_mfma_f32_16x16x32_bf16(af[mm], uf[nn], accu[mm][nn], 0, 0, 0);
                }
        }
        __syncthreads();
    }

    // epilogue: h = w * silu(g)*u -> Hbuf bf16 (pre-scaled by routing weight)
#pragma unroll
    for (int mm = 0; mm < 2; ++mm) {
#pragma unroll
        for (int r = 0; r < 4; ++r) {
            int lr = wm + mm * 16 + fq * 4 + r;
            int grow = row0 + lr;
            if (grow < n_e) {
                float w = tws[lr];
                ushort* hrow = Hbuf + (size_t)(base + grow) * F_ + f0 + wn;
#pragma unroll
                for (int nn = 0; nn < 4; ++nn) {
                    float g = accg[mm][nn][r];
                    float u = accu[mm][nn][r];
                    float h = w * (g / (1.f + __expf(-g))) * u;
                    hrow[nn * 16 + fr] = f2bf(h);
                }
            }
        }
    }
}

// ---------------- pass B: out (+)= H @ wd^T ----------------
// grid: (D_/BN=16, rows/BM, NE or 1); block 512
__global__ __launch_bounds__(512) void k_ffn2(const ushort* __restrict__ Hbuf,
                                              const ushort* __restrict__ wdb,
                                              const ushort* __restrict__ swdb,
                                              const int* __restrict__ meta,
                                              const int* __restrict__ tok_sorted,
                                              float* __restrict__ out,
                                              int shared_pass) {
    const int e = shared_pass ? NE : (int)blockIdx.z;
    int n_e, base;
    if (e < NE) { n_e = meta[e]; base = meta[32 + e]; }
    else        { n_e = NTOK;    base = SHARED_BASE; }
    const int row0 = blockIdx.y * BM;
    if (row0 >= n_e) return;
    const int d0 = blockIdx.x * BN;
    const ushort* wd = (e < NE) ? wdb + (size_t)e * D_ * F_ : swdb;

    __shared__ __align__(16) ushort As[BM * BK];
    __shared__ __align__(16) ushort Bs[BN * BK];
    __shared__ int tks[BM];

    const int tid = threadIdx.x;
    const int wv = tid >> 6, lane = tid & 63;
    if (tid < BM) {
        int r = row0 + tid;
        tks[tid] = (r < n_e) ? ((e < NE) ? tok_sorted[base + r] : r) : -1;
    }
    __syncthreads();

    const int c0 = wv * 64 + lane, c1 = c0 + 512;
    const int rA0 = c0 >> 3, rA1 = c1 >> 3;
    const int ch0 = ((c0 & 7) ^ (rA0 & 7)) * 8;
    const int ch1 = ((c1 & 7) ^ (rA1 & 7)) * 8;
    const ushort* srcA0 = Hbuf + (size_t)(base + row0 + rA0) * F_ + ch0;
    const ushort* srcA1 = Hbuf + (size_t)(base + row0 + rA1) * F_ + ch1;
    const ushort* srcB0 = wd + (size_t)(d0 + rA0) * F_ + ch0;
    const ushort* srcB1 = wd + (size_t)(d0 + rA1) * F_ + ch1;
    char* lA = (char*)As + wv * 1024;
    char* lB = (char*)Bs + wv * 1024;

    f32x4 acc[2][4] = {};
    const int wm = (wv >> 1) * 32, wn = (wv & 1) * 64;
    const int fr = lane & 15, fq = lane >> 4;
    const int sw = fr & 7;
    const int rc0 = ((fq ^ sw) * 8);
    const int rc1 = (((4 + fq) ^ sw) * 8);

    for (int k0 = 0; k0 < F_; k0 += BK) {
        gll16(srcA0 + k0, lA); gll16(srcA1 + k0, lA + 8192);
        gll16(srcB0 + k0, lB); gll16(srcB1 + k0, lB + 8192);
        __syncthreads();
#pragma unroll
        for (int kk = 0; kk < 2; ++kk) {
            const int rc = kk ? rc1 : rc0;
            short8 af[2], bf[4];
#pragma unroll
            for (int mm = 0; mm < 2; ++mm)
                af[mm] = *reinterpret_cast<const short8*>(&As[(wm + mm * 16 + fr) * BK + rc]);
#pragma unroll
            for (int nn = 0; nn < 4; ++nn)
                bf[nn] = *reinterpret_cast<const short8*>(&Bs[(wn + nn * 16 + fr) * BK + rc]);
#pragma unroll
            for (int mm = 0; mm < 2; ++mm)
#pragma unroll
                for (int nn = 0; nn < 4; ++nn)
                    acc[mm][nn] = __builtin_amdgcn_mfma_f32_16x16x32_bf16(af[mm], bf[nn], acc[mm][nn], 0, 0, 0);
        }
        __syncthreads();
    }

#pragma unroll
    for (int mm = 0; mm < 2; ++mm) {
#pragma unroll
        for (int r = 0; r < 4; ++r) {
            int lr = wm + mm * 16 + fq * 4 + r;
            int slot = row0 + lr;
            if (slot < n_e) {
                int t = tks[lr];
                float* orow = out + (size_t)t * D_ + d0 + wn;
#pragma unroll
                for (int nn = 0; nn < 4; ++nn) {
                    float val = acc[mm][nn][r];
                    if (shared_pass) orow[nn * 16 + fr] = val;
                    else atomicAdd(&orow[nn * 16 + fr], val);
                }
            }
        }
    }
}

extern "C" void kernel_launch(void* const* d_in, const int* in_sizes, int n_in,
                              void* d_out, int out_size, void* d_ws, size_t ws_size,
                              hipStream_t stream) {
    const float* x        = (const float*)d_in[0];
    const float* gate_w   = (const float*)d_in[1];
    const float* w_gate   = (const float*)d_in[2];
    const float* w_up     = (const float*)d_in[3];
    const float* w_down   = (const float*)d_in[4];
    const float* sw_gate  = (const float*)d_in[5];
    const float* sw_up    = (const float*)d_in[6];
    const float* sw_down  = (const float*)d_in[7];
    const float* expert_bias = (const float*)d_in[8];
    float* out = (float*)d_out;

    const size_t NW = (size_t)NE * F_ * D_;
    const size_t NSW = (size_t)F_ * D_;
    const size_t NX = (size_t)NTOK * D_;

    char* ws = (char*)d_ws;
    size_t off = 0;
    ushort* xb   = (ushort*)(ws + off); off += NX * 2;
    ushort* wgb  = (ushort*)(ws + off); off += NW * 2;
    ushort* wub  = (ushort*)(ws + off); off += NW * 2;
    ushort* wdb  = (ushort*)(ws + off); off += NW * 2;
    ushort* swgb = (ushort*)(ws + off); off += NSW * 2;
    ushort* swub = (ushort*)(ws + off); off += NSW * 2;
    ushort* swdb = (ushort*)(ws + off); off += NSW * 2;
    ushort* Hbuf = (ushort*)(ws + off); off += (size_t)NTOT * F_ * 2;
    int* tok_sorted = (int*)(ws + off); off += NPAIR * sizeof(int);
    float* w_sorted = (float*)(ws + off); off += NPAIR * sizeof(float);
    int* topk_idx = (int*)(ws + off); off += NTOK * 2 * sizeof(int);
    float* topk_w = (float*)(ws + off); off += NTOK * 2 * sizeof(float);
    int* meta = (int*)(ws + off); off += 256;

    k_route<<<NTOK / 4, 256, 0, stream>>>(x, gate_w, expert_bias, topk_idx, topk_w);
    k_zero_meta<<<1, 64, 0, stream>>>(meta);
    k_count<<<NTOK / 256, 256, 0, stream>>>(topk_idx, meta);
    k_prefix<<<1, 1, 0, stream>>>(meta);
    k_scatter<<<NTOK / 256, 256, 0, stream>>>(topk_idx, topk_w, meta, tok_sorted, w_sorted);

    auto cvt = [&](const float* s, ushort* d, size_t n) {
        int n8 = (int)(n / 8);
        int blocks = (n8 + 255) / 256;
        if (blocks > 4096) blocks = 4096;
        k_cvt<<<blocks, 256, 0, stream>>>(s, d, n8);
    };
    cvt(x, xb, NX);
    cvt(w_gate, wgb, NW);
    cvt(w_up, wub, NW);
    cvt(w_down, wdb, NW);
    cvt(sw_gate, swgb, NSW);
    cvt(sw_up, swub, NSW);
    cvt(sw_down, swdb, NSW);

    dim3 g1(F_ / BN, NTOK / BM, NE + 1);
    k_ffn1<<<g1, 512, 0, stream>>>(xb, wgb, wub, swgb, swub, meta, tok_sorted, w_sorted, Hbuf);

    dim3 g2s(D_ / BN, NTOK / BM, 1);
    k_ffn2<<<g2s, 512, 0, stream>>>(Hbuf, wdb, swdb, meta, tok_sorted, out, 1);
    dim3 g2r(D_ / BN, NTOK / BM, NE);
    k_ffn2<<<g2r, 512, 0, stream>>>(Hbuf, wdb, swdb, meta, tok_sorted, out, 0);
}